// Round 8
// baseline (1154.880 us; speedup 1.0000x reference)
//
#include <hip/hip_runtime.h>
#include <hip/hip_bf16.h>
#include <math.h>

#define DIMC 64
#define C3 192
#define NHEADS 6
#define DH 32
#define WSZ 8
#define SHIFTV 4
#define HIDC 128
#define FULLR 256
#define HALFR 128

typedef __attribute__((ext_vector_type(8))) short bf16x8;
typedef __attribute__((ext_vector_type(4))) float f32x4;

__device__ __forceinline__ float gelu_f(float x){
    return 0.5f * x * (1.0f + erff(x * 0.70710678118654752440f));
}
__device__ __forceinline__ unsigned short f2bf(float f){
    union { float f; unsigned u; } v; v.f = f;
    unsigned r = (v.u + 0x7FFF + ((v.u >> 16) & 1)) >> 16;
    return (unsigned short)r;
}
__device__ __forceinline__ float bf2f(unsigned short h){
    union { unsigned u; float f; } v; v.u = ((unsigned)h) << 16;
    return v.f;
}

// ---------------- DWT: ll fp32 (plane), high bf16 (window-token-major, roll folded in)
__global__ __launch_bounds__(256) void k_dwt(const float* __restrict__ x, float* __restrict__ ll,
                                             unsigned short* __restrict__ high, int nb, int b0){
    int idx = blockIdx.x * 256 + threadIdx.x;
    int total = nb << 19;
    if (idx >= total) return;
    int w4 = idx & 63;
    int h  = (idx >> 6) & 127;
    int c  = (idx >> 13) & 63;
    int b  = idx >> 19;
    const float* xp = x + (((size_t)(b0 + b) * DIMC + c) * FULLR + 2*h) * FULLR + 4*w4;
    float4 r0 = *(const float4*)xp;
    float4 r1 = *(const float4*)(xp + FULLR);
    size_t lbase = (((size_t)b*64 + c) << 14) + h*128 + w4*2;
    float x1a = 0.5f*r0.x, x3a = 0.5f*r0.y, x2a = 0.5f*r1.x, x4a = 0.5f*r1.y;
    float x1b = 0.5f*r0.z, x3b = 0.5f*r0.w, x2b = 0.5f*r1.z, x4b = 0.5f*r1.w;
    float2 v;
    v.x = x1a + x2a + x3a + x4a;           v.y = x1b + x2b + x3b + x4b;
    *(float2*)&ll[lbase] = v;
    int hs = (h + SHIFTV) & 127;  int wh = hs >> 3; int rr = hs & 7;
    int ws = (2*w4 + SHIFTV) & 127; int ww = ws >> 3; int cc = ws & 7;
    size_t wbase = ((size_t)(b*256 + wh*16 + ww)) * 12288 + rr*8 + cc;
    unsigned u;
    u = (unsigned)f2bf(-x1a - x2a + x3a + x4a) | ((unsigned)f2bf(-x1b - x2b + x3b + x4b) << 16);
    *(unsigned*)&high[wbase + (size_t)c*64] = u;
    u = (unsigned)f2bf(-x1a + x2a - x3a + x4a) | ((unsigned)f2bf(-x1b + x2b - x3b + x4b) << 16);
    *(unsigned*)&high[wbase + (size_t)(64 + c)*64] = u;
    u = (unsigned)f2bf( x1a - x2a - x3a + x4a) | ((unsigned)f2bf( x1b - x2b - x3b + x4b) << 16);
    *(unsigned*)&high[wbase + (size_t)(128 + c)*64] = u;
}

// ---------------- gap
__global__ __launch_bounds__(256) void k_gap(const float* __restrict__ ll, float* __restrict__ gap){
    int bc = blockIdx.x;
    const float* p = ll + (size_t)bc * 16384;
    float s = 0.f;
    for (int i = threadIdx.x; i < 16384; i += 256) s += p[i];
    __shared__ float red[256];
    red[threadIdx.x] = s; __syncthreads();
    for (int st = 128; st > 0; st >>= 1){
        if (threadIdx.x < st) red[threadIdx.x] += red[threadIdx.x + st];
        __syncthreads();
    }
    if (threadIdx.x == 0) gap[bc] = red[0] * (1.0f/16384.0f);
}

// ---------------- gate MLP
__global__ __launch_bounds__(256) void k_gate(const float* __restrict__ gap, const float* __restrict__ w1,
                                              const float* __restrict__ w2, float* __restrict__ gate){
    int b = blockIdx.x;
    __shared__ float hid[48];
    __shared__ float g[64];
    if (threadIdx.x < 64) g[threadIdx.x] = gap[b*64 + threadIdx.x];
    __syncthreads();
    if (threadIdx.x < 48){
        float s = 0.f;
        for (int c = 0; c < 64; c++) s += g[c] * w1[threadIdx.x*64 + c];
        hid[threadIdx.x] = gelu_f(s);
    }
    __syncthreads();
    if (threadIdx.x < C3){
        float s = 0.f;
        for (int j = 0; j < 48; j++) s += hid[j] * w2[threadIdx.x*48 + j];
        gate[b*C3 + threadIdx.x] = 1.0f / (1.0f + expf(-s));
    }
}

// ---------------- weights -> bf16, rel bias table
__global__ __launch_bounds__(256) void k_cvt(const float* __restrict__ wq, const float* __restrict__ wp,
    const float* __restrict__ rel_table, const int* __restrict__ rel_idx, const float* __restrict__ wo,
    const float* __restrict__ wi,
    unsigned short* __restrict__ wqb, unsigned short* __restrict__ wpb, float* __restrict__ bias6,
    unsigned short* __restrict__ wob, unsigned short* __restrict__ wib){
    int idx = blockIdx.x*256 + threadIdx.x;
    if (idx < 576*192) wqb[idx] = f2bf(wq[idx]);
    if (idx < 192*192) wpb[idx] = f2bf(wp[idx]);
    if (idx < 64*128)  wob[idx] = f2bf(wo[idx]);
    if (idx < 256*64)  wib[idx] = f2bf(wi[idx]);
    if (idx < 6*64*64){
        int h = idx >> 12; int ij = idx & 4095;
        bias6[idx] = rel_table[rel_idx[ij]*NHEADS + h];
    }
}

// ---------------- fused shifted-window MHSA via MFMA, in-place on window-major high
__global__ __launch_bounds__(256, 3) void k_attn(unsigned short* __restrict__ high,
    const unsigned short* __restrict__ wqb, const unsigned short* __restrict__ wpb,
    const float* __restrict__ bqkv, const float* __restrict__ bproj,
    const float* __restrict__ bias6, const float* __restrict__ lnw, const float* __restrict__ lnb,
    const float* __restrict__ gate, const float* __restrict__ gm_p, const float* __restrict__ gc_p)
{
    __shared__ __align__(16) unsigned short xb[64][200];
    __shared__ __align__(16) unsigned short qs[64][40];
    __shared__ __align__(16) unsigned short ks2[64][40];
    __shared__ __align__(16) unsigned short vt[32][72];
    __shared__ __align__(16) unsigned short ps[64][72];
    __shared__ float st_s[4][64], st_ss[4][64];
    __shared__ float mu_s[64], rs_s[64];

    int tid = threadIdx.x;
    int lane = tid & 63;
    int wv = tid >> 6;
    int lrow = lane & 15;
    int lkg  = lane >> 4;
    int blk = blockIdx.x;
    int b  = blk >> 8;
    size_t wbase = (size_t)blk * 12288;
    const float scale = 0.17677669529663687f;
    float gm = gm_p[0], gc = gc_p[0];

    int t = lane, part = wv;
    float vals[48];
    {
        float s = 0.f, ss = 0.f;
        #pragma unroll
        for (int i = 0; i < 48; i++){
            float v = bf2f(high[wbase + (size_t)(part*48 + i)*64 + t]);
            vals[i] = v; s += v; ss += v*v;
        }
        st_s[part][t] = s; st_ss[part][t] = ss;
    }
    __syncthreads();
    if (tid < 64){
        float s = st_s[0][tid]+st_s[1][tid]+st_s[2][tid]+st_s[3][tid];
        float ss = st_ss[0][tid]+st_ss[1][tid]+st_ss[2][tid]+st_ss[3][tid];
        float mu = s*(1.f/C3);
        float var = ss*(1.f/C3) - mu*mu;
        mu_s[tid] = mu; rs_s[tid] = rsqrtf(var + 1e-6f);
    }
    __syncthreads();
    {
        float mu = mu_s[t], rs = rs_s[t];
        #pragma unroll
        for (int i8 = 0; i8 < 6; i8++){
            bf16x8 pk;
            #pragma unroll
            for (int jj = 0; jj < 8; jj++){
                int c = part*48 + i8*8 + jj;
                float nv = (vals[i8*8+jj] - mu) * rs * lnw[c] + lnb[c];
                pk[jj] = (short)f2bf(nv);
            }
            *(bf16x8*)&xb[t][part*48 + i8*8] = pk;
        }
    }
    __syncthreads();

    f32x4 pacc[3][4];
    #pragma unroll
    for (int mt3 = 0; mt3 < 3; mt3++)
        #pragma unroll
        for (int nt = 0; nt < 4; nt++) pacc[mt3][nt] = (f32x4){0.f,0.f,0.f,0.f};

    for (int h = 0; h < NHEADS; h++){
        f32x4 acc[6];
        #pragma unroll
        for (int nt = 0; nt < 6; nt++) acc[nt] = (f32x4){0.f,0.f,0.f,0.f};
        for (int ksU = 0; ksU < 6; ksU++){
            int c0 = ksU*32 + lkg*8;
            bf16x8 a = *(const bf16x8*)&xb[wv*16 + lrow][c0];
            #pragma unroll
            for (int nt = 0; nt < 6; nt++){
                int which = nt >> 1;
                int gr = which*C3 + h*32 + (nt&1)*16 + lrow;
                bf16x8 bb = *(const bf16x8*)&wqb[(size_t)gr*C3 + c0];
                acc[nt] = __builtin_amdgcn_mfma_f32_16x16x32_bf16(a, bb, acc[nt], 0, 0, 0);
            }
        }
        #pragma unroll
        for (int nt = 0; nt < 6; nt++){
            int which = nt >> 1;
            int d = (nt&1)*16 + lrow;
            float bias = bqkv[which*C3 + h*32 + d];
            #pragma unroll
            for (int r = 0; r < 4; r++){
                int row = wv*16 + lkg*4 + r;
                float v = acc[nt][r] + bias;
                if (which == 0)      qs[row][d]  = f2bf(v * scale);
                else if (which == 1) ks2[row][d] = f2bf(v);
                else                 vt[d][row]  = f2bf(v);
            }
        }
        __syncthreads();

        // scores + softmax (no max-subtraction: |s| < ~1, exp is range-safe)
        f32x4 sacc[4];
        {
            bf16x8 a = *(const bf16x8*)&qs[wv*16 + lrow][lkg*8];
            #pragma unroll
            for (int nt = 0; nt < 4; nt++){
                bf16x8 bb = *(const bf16x8*)&ks2[nt*16 + lrow][lkg*8];
                f32x4 z = (f32x4){0.f,0.f,0.f,0.f};
                sacc[nt] = __builtin_amdgcn_mfma_f32_16x16x32_bf16(a, bb, z, 0, 0, 0);
            }
        }
        {
            #pragma unroll
            for (int r = 0; r < 4; r++){
                int i = wv*16 + lkg*4 + r;
                float pv[4];
                float s = 0.f;
                #pragma unroll
                for (int nt = 0; nt < 4; nt++){
                    pv[nt] = __expf(sacc[nt][r] + bias6[h*4096 + i*64 + nt*16 + lrow]);
                    s += pv[nt];
                }
                s += __shfl_xor(s, 1); s += __shfl_xor(s, 2);
                s += __shfl_xor(s, 4); s += __shfl_xor(s, 8);
                float inv = 1.0f / s;
                #pragma unroll
                for (int nt = 0; nt < 4; nt++) ps[i][nt*16 + lrow] = f2bf(pv[nt] * inv);
            }
        }
        __syncthreads();

        f32x4 oacc[2];
        #pragma unroll
        for (int nt = 0; nt < 2; nt++) oacc[nt] = (f32x4){0.f,0.f,0.f,0.f};
        #pragma unroll
        for (int kst = 0; kst < 2; kst++){
            bf16x8 a = *(const bf16x8*)&ps[wv*16 + lrow][kst*32 + lkg*8];
            #pragma unroll
            for (int nt = 0; nt < 2; nt++){
                bf16x8 bb = *(const bf16x8*)&vt[nt*16 + lrow][kst*32 + lkg*8];
                oacc[nt] = __builtin_amdgcn_mfma_f32_16x16x32_bf16(a, bb, oacc[nt], 0, 0, 0);
            }
        }
        #pragma unroll
        for (int nt = 0; nt < 2; nt++)
            #pragma unroll
            for (int r = 0; r < 4; r++)
                qs[wv*16 + lkg*4 + r][nt*16 + lrow] = f2bf(oacc[nt][r]);
        __syncthreads();

        #pragma unroll
        for (int mt3 = 0; mt3 < 3; mt3++){
            int o = wv*48 + mt3*16 + lrow;
            bf16x8 a = *(const bf16x8*)&wpb[(size_t)o*C3 + h*32 + lkg*8];
            #pragma unroll
            for (int nt = 0; nt < 4; nt++){
                bf16x8 bb = *(const bf16x8*)&qs[nt*16 + lrow][lkg*8];
                pacc[mt3][nt] = __builtin_amdgcn_mfma_f32_16x16x32_bf16(a, bb, pacc[mt3][nt], 0, 0, 0);
            }
        }
        __syncthreads();
    }

    #pragma unroll
    for (int mt3 = 0; mt3 < 3; mt3++){
        #pragma unroll
        for (int r = 0; r < 4; r++){
            int o = wv*48 + mt3*16 + lkg*4 + r;
            float bias = bproj[o];
            float gf = 1.0f + gc * (gate[b*C3 + o] - 0.5f) * 2.0f;
            #pragma unroll
            for (int nt = 0; nt < 4; nt++){
                int token = nt*16 + lrow;
                size_t gi = wbase + (size_t)o*64 + token;
                float orig = bf2f(high[gi]);
                high[gi] = f2bf((orig + gm*(pacc[mt3][nt][r] + bias)) * gf);
            }
        }
    }
}

// ---------------- aux depthwise 3x3 + gelu
__global__ __launch_bounds__(256) void k_dwc_aux(const float* __restrict__ ll, const float* __restrict__ dw,
                                                 float* __restrict__ tmp, int nb){
    int idx = blockIdx.x*256 + threadIdx.x;
    int total = nb << 17;
    if (idx >= total) return;
    int c0 = (idx & 31) * 4;
    int h  = (idx >> 5) & 127;
    int ch = (idx >> 12) & 63;
    int b  = idx >> 18;
    const float* wd = dw + ch*9;
    const float* plane = ll + (((size_t)b*64 + ch) << 14);
    float acc[4] = {0.f, 0.f, 0.f, 0.f};
    #pragma unroll
    for (int dy = 0; dy < 3; dy++){
        int y = h + dy - 1;
        if (y < 0 || y > 127) continue;
        const float* rp = plane + y*128;
        float4 v = *(const float4*)(rp + c0);
        float l = (c0 > 0)   ? rp[c0 - 1] : 0.f;
        float rg = (c0 < 124) ? rp[c0 + 4] : 0.f;
        float w0 = wd[dy*3+0], w1 = wd[dy*3+1], w2 = wd[dy*3+2];
        acc[0] += w0*l   + w1*v.x + w2*v.y;
        acc[1] += w0*v.x + w1*v.y + w2*v.z;
        acc[2] += w0*v.y + w1*v.z + w2*v.w;
        acc[3] += w0*v.z + w1*v.w + w2*rg;
    }
    float4 o;
    o.x = gelu_f(acc[0]); o.y = gelu_f(acc[1]); o.z = gelu_f(acc[2]); o.w = gelu_f(acc[3]);
    *(float4*)&tmp[(((size_t)b*64 + ch) << 14) + h*128 + c0] = o;
}

// ---------------- aux pointwise, LDS-tiled
__global__ __launch_bounds__(256) void k_aux_pw(const float* __restrict__ ll, const float* __restrict__ tmp,
                                                const float* __restrict__ pw, const float* __restrict__ ga_p,
                                                float* __restrict__ rll, int nb){
    __shared__ float tl[64][65];
    int tid = threadIdx.x;
    int blk = blockIdx.x;
    int b = blk >> 8;
    int pix0 = (blk & 255) * 64;
    for (int idx = tid; idx < 4096; idx += 256){
        int c = idx >> 6, px = idx & 63;
        tl[c][px] = tmp[((size_t)(b*64 + c) << 14) + pix0 + px];
    }
    __syncthreads();
    int px = tid & 63, cq = tid >> 6;
    float ga = ga_p[0];
    for (int og = 0; og < 2; og++){
        int ob = cq*16 + og*8;
        float acc[8] = {0,0,0,0,0,0,0,0};
        for (int c = 0; c < 64; c++){
            float v = tl[c][px];
            #pragma unroll
            for (int j = 0; j < 8; j++) acc[j] += v * pw[(ob+j)*64 + c];
        }
        #pragma unroll
        for (int j = 0; j < 8; j++){
            size_t gi = ((size_t)(b*64 + ob + j) << 14) + pix0 + px;
            rll[gi] = ll[gi] + ga * acc[j];
        }
    }
}

// ---------------- fused IWT + proj + residual -> y1(bf16)  THEN  LN + conv1x1(64->256) -> h(bf16)
__global__ __launch_bounds__(256) void k_iwt_ffn(const float* __restrict__ rll,
    const unsigned short* __restrict__ high, const float* __restrict__ x,
    const float* __restrict__ wao, const float* __restrict__ lnw, const float* __restrict__ lnb,
    const unsigned short* __restrict__ wib,
    unsigned short* __restrict__ y1b, unsigned short* __restrict__ h, int nb, int b0)
{
    __shared__ __align__(16) char smem[52608];
    float* wt_s  = (float*)smem;                          // [64][65]  (phase A)
    unsigned short* xn = (unsigned short*)smem;           // [64][72]  (phase B/C, overlays wt)
    float* dbuf = (float*)(smem + 16640);                 // [64][65]
    float* xt   = (float*)(smem + 33280);                 // [64][65]
    unsigned short* ho = (unsigned short*)(smem + 16640); // [128][72] (phase C, overlays dbuf/xt)
    float* pss  = (float*)(smem + 49920);                 // [4][64]
    float* psss = (float*)(smem + 50944);                 // [4][64]

    int tid = threadIdx.x;
    for (int idx = tid; idx < 4096; idx += 256){
        int o = idx >> 6, i = idx & 63;
        wt_s[i*65 + o] = wao[o*64 + i];
    }
    int blk = blockIdx.x;
    int seg = blk & 3;
    int ph  = (blk >> 2) & 255;
    int b   = blk >> 10;
    int pw0 = seg * 64;
    int h2 = ph >> 1, p = ph & 1;
    size_t xbase = ((size_t)(b0 + b) * DIMC) * 65536;
    int px = tid & 63;
    int ci = tid >> 6;
    int pwv = pw0 + px;
    int w2 = pwv >> 1, q = pwv & 1;
    float shl = q ? 1.f : -1.f;
    float slh = p ? 1.f : -1.f;
    float shh = (p == q) ? 1.f : -1.f;
    int hs = (h2 + SHIFTV) & 127; int wh = hs >> 3; int rr = hs & 7;
    int ws = (w2 + SHIFTV) & 127; int ww = ws >> 3; int cc = ws & 7;
    size_t wbase = ((size_t)(b*256 + wh*16 + ww)) * 12288 + rr*8 + cc;

    for (int i = ci; i < 64; i += 4){
        float llv = rll[(((size_t)b*64 + i)*128 + h2)*128 + w2];
        float hl = bf2f(high[wbase + (size_t)i*64]);
        float lh = bf2f(high[wbase + (size_t)(64 + i)*64]);
        float hh = bf2f(high[wbase + (size_t)(128 + i)*64]);
        float iw = 0.5f * (llv + shl*hl + slh*lh + shh*hh);
        float xv = x[xbase + (size_t)i*65536 + (size_t)ph*256 + pwv];
        xt[i*65 + px] = xv;
        dbuf[i*65 + px] = iw - xv;
    }
    __syncthreads();

    // y1 tile GEMM (thread px,ci owns o = ci, ci+4, ..., ci+60)
    float yv[16];
    float s = 0.f, ss = 0.f;
    #pragma unroll
    for (int k16 = 0; k16 < 16; k16++){
        int o = ci + 4*k16;
        float s0=0.f,s1=0.f,s2=0.f,s3=0.f;
        for (int i = 0; i < 64; i += 4){
            s0 += dbuf[(i+0)*65 + px] * wt_s[(i+0)*65 + o];
            s1 += dbuf[(i+1)*65 + px] * wt_s[(i+1)*65 + o];
            s2 += dbuf[(i+2)*65 + px] * wt_s[(i+2)*65 + o];
            s3 += dbuf[(i+3)*65 + px] * wt_s[(i+3)*65 + o];
        }
        float v = xt[o*65 + px] + (s0+s1)+(s2+s3);
        yv[k16] = v;
        s += v; ss += v*v;
        y1b[(((size_t)(b*64 + o)) << 16) + (size_t)ph*256 + pwv] = f2bf(v);
    }
    pss[ci*64 + px] = s; psss[ci*64 + px] = ss;
    __syncthreads();

    // LN per pixel (all 4 threads sharing px duplicate the stats)
    {
        float st = pss[px] + pss[64 + px] + pss[128 + px] + pss[192 + px];
        float sst = psss[px] + psss[64 + px] + psss[128 + px] + psss[192 + px];
        float mu = st * (1.f/64.f);
        float var = sst * (1.f/64.f) - mu*mu;
        float rs = rsqrtf(var + 1e-6f);
        #pragma unroll
        for (int k16 = 0; k16 < 16; k16++){
            int o = ci + 4*k16;
            xn[px*72 + o] = f2bf((yv[k16] - mu) * rs * lnw[o] + lnb[o]);
        }
    }
    __syncthreads();

    // conv1x1 64->256 via MFMA
    int lane = tid & 63;
    int wv = tid >> 6;
    int lrow = lane & 15;
    int lkg  = lane >> 4;
    for (int hh = 0; hh < 2; hh++){
        int oc0 = hh*128;
        f32x4 acc[8];
        #pragma unroll
        for (int nt = 0; nt < 8; nt++) acc[nt] = (f32x4){0.f,0.f,0.f,0.f};
        #pragma unroll
        for (int kst = 0; kst < 2; kst++){
            bf16x8 a = *(const bf16x8*)&xn[(wv*16 + lrow)*72 + kst*32 + lkg*8];
            #pragma unroll
            for (int nt = 0; nt < 8; nt++){
                bf16x8 bb = *(const bf16x8*)&wib[(size_t)(oc0 + nt*16 + lrow)*64 + kst*32 + lkg*8];
                acc[nt] = __builtin_amdgcn_mfma_f32_16x16x32_bf16(a, bb, acc[nt], 0, 0, 0);
            }
        }
        #pragma unroll
        for (int nt = 0; nt < 8; nt++)
            #pragma unroll
            for (int r = 0; r < 4; r++)
                ho[(nt*16 + lrow)*72 + wv*16 + lkg*4 + r] = f2bf(acc[nt][r]);
        __syncthreads();
        for (int idx = tid; idx < 1024; idx += 256){
            int oc = idx >> 3, p8 = idx & 7;
            bf16x8 v = *(const bf16x8*)&ho[oc*72 + p8*8];
            *(bf16x8*)&h[(size_t)(b*256 + oc0 + oc)*65536 + (size_t)ph*256 + seg*64 + p8*8] = v;
        }
        __syncthreads();
    }
}

// ---------------- spectral kernel: k_c = irfft2(W_c)
__global__ __launch_bounds__(256) void k_kspec(const float* __restrict__ wr, const float* __restrict__ wi,
                                               float* __restrict__ ks){
    int idx = blockIdx.x*256 + threadIdx.x;
    if (idx >= 128*64) return;
    int ch = idx >> 6;
    int r = (idx >> 3) & 7, c = idx & 7;
    float s = 0.f;
    for (int u = 0; u < 8; u++){
        for (int v = 0; v < 8; v++){
            float re, im;
            if (v <= 4){ re = wr[ch*40 + u*5 + v]; im = wi[ch*40 + u*5 + v]; }
            else { int u2 = (8-u)&7; int v2 = 8-v; re = wr[ch*40 + u2*5 + v2]; im = -wi[ch*40 + u2*5 + v2]; }
            float ang = (float)(u*r + v*c) * 0.78539816339744831f;
            float cs, sn; __sincosf(ang, &sn, &cs);
            s += re * cs - im * sn;
        }
    }
    ks[idx] = s * (1.0f/64.0f);
}

// ---------------- circulant matrices (bf16)
__global__ __launch_bounds__(256) void k_circ(const float* __restrict__ ksp, unsigned short* __restrict__ circ){
    int idx = blockIdx.x*256 + threadIdx.x;
    if (idx >= 128*4096) return;
    int ch = idx >> 12;
    int o = (idx >> 6) & 63;
    int i = idx & 63;
    int dr = ((o >> 3) - (i >> 3)) & 7;
    int dc = ((o & 7) - (i & 7)) & 7;
    circ[idx] = f2bf(ksp[ch*64 + dr*8 + dc]);
}

// ---------------- FFN part B: depthwise 3x3 (8 px/thread, vectorized) -> patch-major hd
__global__ __launch_bounds__(256) void k_ffn_b(const unsigned short* __restrict__ h,
    const float* __restrict__ w_dw, unsigned short* __restrict__ hd, int nb)
{
    int chunk = blockIdx.x*256 + threadIdx.x;
    int total = nb*256*8192;
    if (chunk >= total) return;
    int c0  = (chunk & 31) * 8;
    int r   = (chunk >> 5) & 255;
    int bch = chunk >> 13;
    int ch  = bch & 255;
    const unsigned short* hp = h + ((size_t)bch << 16);
    const float* wd = w_dw + ch*9;
    float acc[8] = {0,0,0,0,0,0,0,0};
    #pragma unroll
    for (int dy = 0; dy < 3; dy++){
        int y = r + dy - 1;
        if (y < 0 || y > 255) continue;
        const unsigned short* rp = hp + y*256;
        bf16x8 v = *(const bf16x8*)&rp[c0];
        float vf[8];
        #pragma unroll
        for (int j = 0; j < 8; j++) vf[j] = bf2f((unsigned short)v[j]);
        float l  = (c0 > 0)   ? bf2f(rp[c0 - 1]) : 0.f;
        float rg = (c0 < 248) ? bf2f(rp[c0 + 8]) : 0.f;
        float w0 = wd[dy*3+0], w1 = wd[dy*3+1], w2 = wd[dy*3+2];
        acc[0] += w0*l + w1*vf[0] + w2*vf[1];
        #pragma unroll
        for (int j = 1; j < 7; j++) acc[j] += w0*vf[j-1] + w1*vf[j] + w2*vf[j+1];
        acc[7] += w0*vf[6] + w1*vf[7] + w2*rg;
    }
    bf16x8 o;
    #pragma unroll
    for (int j = 0; j < 8; j++) o[j] = (short)f2bf(acc[j]);
    int patch = (r >> 3)*32 + (c0 >> 3);
    *(bf16x8*)&hd[((size_t)bch << 16) + (size_t)patch*64 + (r & 7)*8] = o;
}

// ---------------- FFN spectral conv via MFMA circulant GEMM + gelu*gate -> m (bf16)
__global__ __launch_bounds__(256) void k_conv(const unsigned short* __restrict__ hdu,
    const unsigned short* __restrict__ circ, unsigned short* __restrict__ mbuf)
{
    int tid = threadIdx.x;
    int lane = tid & 63;
    int wv = tid >> 6;
    int lrow = lane & 15;
    int lkg  = lane >> 4;
    int blk = blockIdx.x;
    int b   = blk >> 7;
    int chc = (blk >> 5) & 3;
    int pc  = blk & 31;
    int pbase  = pc*32 + (wv >> 1)*16;
    int chbase = chc*32 + (wv & 1)*16;

    for (int c16 = 0; c16 < 16; c16++){
        int ch = chbase + c16;
        const unsigned short* Ab = hdu + (((size_t)(b*256 + ch)) << 16);
        const unsigned short* Bb = circ + (size_t)ch*4096;
        f32x4 acc[4];
        #pragma unroll
        for (int nt = 0; nt < 4; nt++) acc[nt] = (f32x4){0.f,0.f,0.f,0.f};
        #pragma unroll
        for (int kst = 0; kst < 2; kst++){
            bf16x8 a = *(const bf16x8*)&Ab[(size_t)(pbase + lrow)*64 + kst*32 + lkg*8];
            #pragma unroll
            for (int nt = 0; nt < 4; nt++){
                bf16x8 bb = *(const bf16x8*)&Bb[(size_t)(nt*16 + lrow)*64 + kst*32 + lkg*8];
                acc[nt] = __builtin_amdgcn_mfma_f32_16x16x32_bf16(a, bb, acc[nt], 0, 0, 0);
            }
        }
        const unsigned short* Gb = hdu + (((size_t)(b*256 + 128 + ch)) << 16);
        unsigned short* Mb = mbuf + (((size_t)(b*128 + ch)) << 16);
        #pragma unroll
        for (int nt = 0; nt < 4; nt++){
            #pragma unroll
            for (int r = 0; r < 4; r++){
                int patch = pbase + lkg*4 + r;
                int px = nt*16 + lrow;
                float g = bf2f(Gb[(size_t)patch*64 + px]);
                Mb[(size_t)patch*64 + px] = f2bf(gelu_f(acc[nt][r]) * g);
            }
        }
    }
}

// ---------------- FFN out-projection via MFMA: out = y1 + m @ w_out.T
__global__ __launch_bounds__(256) void k_out(const unsigned short* __restrict__ y1b,
    const unsigned short* __restrict__ mbuf, const unsigned short* __restrict__ wob,
    float* __restrict__ out, int b0)
{
    __shared__ __align__(16) unsigned short mlds[2][64][136];
    int tid = threadIdx.x;
    int lane = tid & 63;
    int wv = tid >> 6;
    int lrow = lane & 15;
    int lkg  = lane >> 4;
    int blk = blockIdx.x;
    int b  = blk >> 9;
    int pp = blk & 511;

    for (int it = 0; it < 8; it++){
        int chunk = tid + it*256;
        int ch = chunk >> 4;
        int p = (chunk >> 3) & 1;
        int px8 = chunk & 7;
        bf16x8 v = *(const bf16x8*)&mbuf[(((size_t)(b*128 + ch)) << 16) + (size_t)(2*pp + p)*64 + px8*8];
        #pragma unroll
        for (int j = 0; j < 8; j++) mlds[p][px8*8 + j][ch] = (unsigned short)v[j];
    }
    __syncthreads();

    int p = wv >> 1;
    int ochalf = wv & 1;
    f32x4 acc[2][4];
    #pragma unroll
    for (int mt = 0; mt < 2; mt++)
        #pragma unroll
        for (int nt = 0; nt < 4; nt++) acc[mt][nt] = (f32x4){0.f,0.f,0.f,0.f};
    #pragma unroll
    for (int kst = 0; kst < 4; kst++){
        bf16x8 a0 = *(const bf16x8*)&wob[(size_t)(ochalf*32 + 0  + lrow)*128 + kst*32 + lkg*8];
        bf16x8 a1 = *(const bf16x8*)&wob[(size_t)(ochalf*32 + 16 + lrow)*128 + kst*32 + lkg*8];
        #pragma unroll
        for (int nt = 0; nt < 4; nt++){
            bf16x8 bb = *(const bf16x8*)&mlds[p][nt*16 + lrow][kst*32 + lkg*8];
            acc[0][nt] = __builtin_amdgcn_mfma_f32_16x16x32_bf16(a0, bb, acc[0][nt], 0, 0, 0);
            acc[1][nt] = __builtin_amdgcn_mfma_f32_16x16x32_bf16(a1, bb, acc[1][nt], 0, 0, 0);
        }
    }
    int patchIdx = 2*pp + p;
    int Rb = (patchIdx >> 5) * 8, Cb = (patchIdx & 31) * 8;
    #pragma unroll
    for (int mt = 0; mt < 2; mt++){
        #pragma unroll
        for (int nt = 0; nt < 4; nt++){
            #pragma unroll
            for (int r = 0; r < 4; r++){
                int oc = ochalf*32 + mt*16 + lkg*4 + r;
                int px = nt*16 + lrow;
                int R = Rb + (px >> 3), C = Cb + (px & 7);
                size_t li = (((size_t)(b*64 + oc)) << 16) + (size_t)R*256 + C;
                size_t go = (((size_t)((b0 + b)*64 + oc)) << 16) + (size_t)R*256 + C;
                out[go] = bf2f(y1b[li]) + acc[mt][nt][r];
            }
        }
    }
}

extern "C" void kernel_launch(void* const* d_in, const int* in_sizes, int n_in,
                              void* d_out, int out_size, void* d_ws, size_t ws_size,
                              hipStream_t stream){
    const float* x        = (const float*)d_in[0];
    const float* ln_w     = (const float*)d_in[1];
    const float* ln_b     = (const float*)d_in[2];
    const float* lnh_w    = (const float*)d_in[3];
    const float* lnh_b    = (const float*)d_in[4];
    const float* w_qkv    = (const float*)d_in[5];
    const float* b_qkv    = (const float*)d_in[6];
    const float* w_proj   = (const float*)d_in[7];
    const float* b_proj   = (const float*)d_in[8];
    const float* rel_tab  = (const float*)d_in[9];
    const float* g_main   = (const float*)d_in[10];
    const float* g_aux    = (const float*)d_in[11];
    const float* g_cross  = (const float*)d_in[12];
    const float* aux_dw   = (const float*)d_in[13];
    const float* aux_pw   = (const float*)d_in[14];
    const float* cg_w1    = (const float*)d_in[15];
    const float* cg_w2    = (const float*)d_in[16];
    const float* attn_ow  = (const float*)d_in[17];
    const float* ffn_in_w = (const float*)d_in[18];
    const float* ffn_dw   = (const float*)d_in[19];
    const float* ffn_ow   = (const float*)d_in[20];
    const float* wb_re    = (const float*)d_in[21];
    const float* wb_im    = (const float*)d_in[22];
    const int*   rel_idx  = (const int*)d_in[23];
    float* out = (float*)d_out;
    (void)in_sizes; (void)n_in; (void)out_size;

    const size_t MBsz = (size_t)1 << 20;
    auto need = [&](int nb)->size_t { return (size_t)nb*72*MBsz + 2*MBsz; };
    int nbmax = 4;
    while (nbmax > 1 && need(nbmax) > ws_size) nbmax >>= 1;

    for (int b0 = 0; b0 < 4; b0 += nbmax){
        int nb = nbmax;
        char* p = (char*)d_ws;
        char* U = p;                      p += (size_t)nb*72*MBsz;
        float* gap  = (float*)p;          p += 4096;
        float* gate = (float*)p;          p += 4096;
        float* ksp  = (float*)p;          p += 128*64*4;
        unsigned short* wqb = (unsigned short*)p; p += 576*192*2;
        unsigned short* wpb = (unsigned short*)p; p += 192*192*2;
        float* bias6 = (float*)p;         p += 6*64*64*4;
        unsigned short* circ = (unsigned short*)p; p += 128*4096*2;
        unsigned short* wob  = (unsigned short*)p; p += 64*128*2;
        unsigned short* wib  = (unsigned short*)p; p += 256*64*2;

        // phase-1 overlays (all inside hd's future region [0, nb*32MB))
        float* ll            = (float*)U;                                   // nb*4MB
        unsigned short* highb= (unsigned short*)(U + (size_t)nb*4*MBsz);    // nb*6MB
        float* tmp           = (float*)(U + (size_t)nb*10*MBsz);            // nb*4MB
        float* rll           = (float*)(U + (size_t)nb*14*MBsz);            // nb*4MB
        // phase-2
        unsigned short* hd   = (unsigned short*)U;                          // nb*32MB [0..32)
        unsigned short* h    = (unsigned short*)(U + (size_t)nb*32*MBsz);   // nb*32MB [32..64)
        unsigned short* y1b  = (unsigned short*)(U + (size_t)nb*64*MBsz);   // nb*8MB  [64..72)
        unsigned short* mbuf = (unsigned short*)(U + (size_t)nb*32*MBsz);   // nb*16MB overlays dead h

        k_kspec<<<32, 256, 0, stream>>>(wb_re, wb_im, ksp);
        k_circ<<<2048, 256, 0, stream>>>(ksp, circ);
        k_cvt<<<432, 256, 0, stream>>>(w_qkv, w_proj, rel_tab, rel_idx, ffn_ow, ffn_in_w,
                                       wqb, wpb, bias6, wob, wib);
        k_dwt<<<nb*2048, 256, 0, stream>>>(x, ll, highb, nb, b0);
        k_gap<<<nb*64, 256, 0, stream>>>(ll, gap);
        k_gate<<<nb, 256, 0, stream>>>(gap, cg_w1, cg_w2, gate);
        k_attn<<<nb*256, 256, 0, stream>>>(highb, wqb, wpb, b_qkv, b_proj, bias6,
                                           lnh_w, lnh_b, gate, g_main, g_cross);
        k_dwc_aux<<<nb*512, 256, 0, stream>>>(ll, aux_dw, tmp, nb);
        k_aux_pw<<<nb*256, 256, 0, stream>>>(ll, tmp, aux_pw, g_aux, rll, nb);
        k_iwt_ffn<<<nb*1024, 256, 0, stream>>>(rll, highb, x, attn_ow, ln_w, ln_b, wib,
                                               y1b, h, nb, b0);
        k_ffn_b<<<nb*8192, 256, 0, stream>>>(h, ffn_dw, hd, nb);
        k_conv<<<nb*128, 256, 0, stream>>>(hd, circ, mbuf);
        k_out<<<nb*512, 256, 0, stream>>>(y1b, mbuf, wob, out, b0);
    }
}

// Round 9
// 840.614 us; speedup vs baseline: 1.3739x; 1.3739x over previous
//
#include <hip/hip_runtime.h>
#include <hip/hip_bf16.h>
#include <math.h>

#define DIMC 64
#define C3 192
#define NHEADS 6
#define DH 32
#define WSZ 8
#define SHIFTV 4
#define HIDC 128
#define FULLR 256
#define HALFR 128

typedef __attribute__((ext_vector_type(8))) short bf16x8;
typedef __attribute__((ext_vector_type(4))) float f32x4;

__device__ __forceinline__ float gelu_f(float x){
    return 0.5f * x * (1.0f + erff(x * 0.70710678118654752440f));
}
__device__ __forceinline__ unsigned short f2bf(float f){
    union { float f; unsigned u; } v; v.f = f;
    unsigned r = (v.u + 0x7FFF + ((v.u >> 16) & 1)) >> 16;
    return (unsigned short)r;
}
__device__ __forceinline__ float bf2f(unsigned short h){
    union { unsigned u; float f; } v; v.u = ((unsigned)h) << 16;
    return v.f;
}

// ---------------- DWT: ll fp32 (plane), high bf16 (window-token-major, roll folded in)
__global__ __launch_bounds__(256) void k_dwt(const float* __restrict__ x, float* __restrict__ ll,
                                             unsigned short* __restrict__ high, int nb, int b0){
    int idx = blockIdx.x * 256 + threadIdx.x;
    int total = nb << 19;
    if (idx >= total) return;
    int w4 = idx & 63;
    int h  = (idx >> 6) & 127;
    int c  = (idx >> 13) & 63;
    int b  = idx >> 19;
    const float* xp = x + (((size_t)(b0 + b) * DIMC + c) * FULLR + 2*h) * FULLR + 4*w4;
    float4 r0 = *(const float4*)xp;
    float4 r1 = *(const float4*)(xp + FULLR);
    size_t lbase = (((size_t)b*64 + c) << 14) + h*128 + w4*2;
    float x1a = 0.5f*r0.x, x3a = 0.5f*r0.y, x2a = 0.5f*r1.x, x4a = 0.5f*r1.y;
    float x1b = 0.5f*r0.z, x3b = 0.5f*r0.w, x2b = 0.5f*r1.z, x4b = 0.5f*r1.w;
    float2 v;
    v.x = x1a + x2a + x3a + x4a;           v.y = x1b + x2b + x3b + x4b;
    *(float2*)&ll[lbase] = v;
    int hs = (h + SHIFTV) & 127;  int wh = hs >> 3; int rr = hs & 7;
    int ws = (2*w4 + SHIFTV) & 127; int ww = ws >> 3; int cc = ws & 7;
    size_t wbase = ((size_t)(b*256 + wh*16 + ww)) * 12288 + rr*8 + cc;
    unsigned u;
    u = (unsigned)f2bf(-x1a - x2a + x3a + x4a) | ((unsigned)f2bf(-x1b - x2b + x3b + x4b) << 16);
    *(unsigned*)&high[wbase + (size_t)c*64] = u;
    u = (unsigned)f2bf(-x1a + x2a - x3a + x4a) | ((unsigned)f2bf(-x1b + x2b - x3b + x4b) << 16);
    *(unsigned*)&high[wbase + (size_t)(64 + c)*64] = u;
    u = (unsigned)f2bf( x1a - x2a - x3a + x4a) | ((unsigned)f2bf( x1b - x2b - x3b + x4b) << 16);
    *(unsigned*)&high[wbase + (size_t)(128 + c)*64] = u;
}

// ---------------- gap
__global__ __launch_bounds__(256) void k_gap(const float* __restrict__ ll, float* __restrict__ gap){
    int bc = blockIdx.x;
    const float* p = ll + (size_t)bc * 16384;
    float s = 0.f;
    for (int i = threadIdx.x; i < 16384; i += 256) s += p[i];
    __shared__ float red[256];
    red[threadIdx.x] = s; __syncthreads();
    for (int st = 128; st > 0; st >>= 1){
        if (threadIdx.x < st) red[threadIdx.x] += red[threadIdx.x + st];
        __syncthreads();
    }
    if (threadIdx.x == 0) gap[bc] = red[0] * (1.0f/16384.0f);
}

// ---------------- gate MLP
__global__ __launch_bounds__(256) void k_gate(const float* __restrict__ gap, const float* __restrict__ w1,
                                              const float* __restrict__ w2, float* __restrict__ gate){
    int b = blockIdx.x;
    __shared__ float hid[48];
    __shared__ float g[64];
    if (threadIdx.x < 64) g[threadIdx.x] = gap[b*64 + threadIdx.x];
    __syncthreads();
    if (threadIdx.x < 48){
        float s = 0.f;
        for (int c = 0; c < 64; c++) s += g[c] * w1[threadIdx.x*64 + c];
        hid[threadIdx.x] = gelu_f(s);
    }
    __syncthreads();
    if (threadIdx.x < C3){
        float s = 0.f;
        for (int j = 0; j < 48; j++) s += hid[j] * w2[threadIdx.x*48 + j];
        gate[b*C3 + threadIdx.x] = 1.0f / (1.0f + expf(-s));
    }
}

// ---------------- weights -> bf16, rel bias table
__global__ __launch_bounds__(256) void k_cvt(const float* __restrict__ wq, const float* __restrict__ wp,
    const float* __restrict__ rel_table, const int* __restrict__ rel_idx, const float* __restrict__ wo,
    const float* __restrict__ wi,
    unsigned short* __restrict__ wqb, unsigned short* __restrict__ wpb, float* __restrict__ bias6,
    unsigned short* __restrict__ wob, unsigned short* __restrict__ wib){
    int idx = blockIdx.x*256 + threadIdx.x;
    if (idx < 576*192) wqb[idx] = f2bf(wq[idx]);
    if (idx < 192*192) wpb[idx] = f2bf(wp[idx]);
    if (idx < 64*128)  wob[idx] = f2bf(wo[idx]);
    if (idx < 256*64)  wib[idx] = f2bf(wi[idx]);
    if (idx < 6*64*64){
        int h = idx >> 12; int ij = idx & 4095;
        bias6[idx] = rel_table[rel_idx[ij]*NHEADS + h];
    }
}

// ---------------- fused shifted-window MHSA via MFMA, in-place on window-major high
__global__ __launch_bounds__(256, 3) void k_attn(unsigned short* __restrict__ high,
    const unsigned short* __restrict__ wqb, const unsigned short* __restrict__ wpb,
    const float* __restrict__ bqkv, const float* __restrict__ bproj,
    const float* __restrict__ bias6, const float* __restrict__ lnw, const float* __restrict__ lnb,
    const float* __restrict__ gate, const float* __restrict__ gm_p, const float* __restrict__ gc_p)
{
    __shared__ __align__(16) unsigned short xb[64][200];
    __shared__ __align__(16) unsigned short qs[64][40];
    __shared__ __align__(16) unsigned short ks2[64][40];
    __shared__ __align__(16) unsigned short vt[32][72];
    __shared__ __align__(16) unsigned short ps[64][72];
    __shared__ float st_s[4][64], st_ss[4][64];
    __shared__ float mu_s[64], rs_s[64];

    int tid = threadIdx.x;
    int lane = tid & 63;
    int wv = tid >> 6;
    int lrow = lane & 15;
    int lkg  = lane >> 4;
    int blk = blockIdx.x;
    int b  = blk >> 8;
    size_t wbase = (size_t)blk * 12288;
    const float scale = 0.17677669529663687f;
    float gm = gm_p[0], gc = gc_p[0];

    int t = lane, part = wv;
    float vals[48];
    {
        float s = 0.f, ss = 0.f;
        #pragma unroll
        for (int i = 0; i < 48; i++){
            float v = bf2f(high[wbase + (size_t)(part*48 + i)*64 + t]);
            vals[i] = v; s += v; ss += v*v;
        }
        st_s[part][t] = s; st_ss[part][t] = ss;
    }
    __syncthreads();
    if (tid < 64){
        float s = st_s[0][tid]+st_s[1][tid]+st_s[2][tid]+st_s[3][tid];
        float ss = st_ss[0][tid]+st_ss[1][tid]+st_ss[2][tid]+st_ss[3][tid];
        float mu = s*(1.f/C3);
        float var = ss*(1.f/C3) - mu*mu;
        mu_s[tid] = mu; rs_s[tid] = rsqrtf(var + 1e-6f);
    }
    __syncthreads();
    {
        float mu = mu_s[t], rs = rs_s[t];
        #pragma unroll
        for (int i8 = 0; i8 < 6; i8++){
            bf16x8 pk;
            #pragma unroll
            for (int jj = 0; jj < 8; jj++){
                int c = part*48 + i8*8 + jj;
                float nv = (vals[i8*8+jj] - mu) * rs * lnw[c] + lnb[c];
                pk[jj] = (short)f2bf(nv);
            }
            *(bf16x8*)&xb[t][part*48 + i8*8] = pk;
        }
    }
    __syncthreads();

    f32x4 pacc[3][4];
    #pragma unroll
    for (int mt3 = 0; mt3 < 3; mt3++)
        #pragma unroll
        for (int nt = 0; nt < 4; nt++) pacc[mt3][nt] = (f32x4){0.f,0.f,0.f,0.f};

    for (int h = 0; h < NHEADS; h++){
        f32x4 acc[6];
        #pragma unroll
        for (int nt = 0; nt < 6; nt++) acc[nt] = (f32x4){0.f,0.f,0.f,0.f};
        for (int ksU = 0; ksU < 6; ksU++){
            int c0 = ksU*32 + lkg*8;
            bf16x8 a = *(const bf16x8*)&xb[wv*16 + lrow][c0];
            #pragma unroll
            for (int nt = 0; nt < 6; nt++){
                int which = nt >> 1;
                int gr = which*C3 + h*32 + (nt&1)*16 + lrow;
                bf16x8 bb = *(const bf16x8*)&wqb[(size_t)gr*C3 + c0];
                acc[nt] = __builtin_amdgcn_mfma_f32_16x16x32_bf16(a, bb, acc[nt], 0, 0, 0);
            }
        }
        #pragma unroll
        for (int nt = 0; nt < 6; nt++){
            int which = nt >> 1;
            int d = (nt&1)*16 + lrow;
            float bias = bqkv[which*C3 + h*32 + d];
            #pragma unroll
            for (int r = 0; r < 4; r++){
                int row = wv*16 + lkg*4 + r;
                float v = acc[nt][r] + bias;
                if (which == 0)      qs[row][d]  = f2bf(v * scale);
                else if (which == 1) ks2[row][d] = f2bf(v);
                else                 vt[d][row]  = f2bf(v);
            }
        }
        __syncthreads();

        // scores + softmax (no max-subtraction: |s| small, exp range-safe)
        f32x4 sacc[4];
        {
            bf16x8 a = *(const bf16x8*)&qs[wv*16 + lrow][lkg*8];
            #pragma unroll
            for (int nt = 0; nt < 4; nt++){
                bf16x8 bb = *(const bf16x8*)&ks2[nt*16 + lrow][lkg*8];
                f32x4 z = (f32x4){0.f,0.f,0.f,0.f};
                sacc[nt] = __builtin_amdgcn_mfma_f32_16x16x32_bf16(a, bb, z, 0, 0, 0);
            }
        }
        {
            #pragma unroll
            for (int r = 0; r < 4; r++){
                int i = wv*16 + lkg*4 + r;
                float pv[4];
                float s = 0.f;
                #pragma unroll
                for (int nt = 0; nt < 4; nt++){
                    pv[nt] = __expf(sacc[nt][r] + bias6[h*4096 + i*64 + nt*16 + lrow]);
                    s += pv[nt];
                }
                s += __shfl_xor(s, 1); s += __shfl_xor(s, 2);
                s += __shfl_xor(s, 4); s += __shfl_xor(s, 8);
                float inv = 1.0f / s;
                #pragma unroll
                for (int nt = 0; nt < 4; nt++) ps[i][nt*16 + lrow] = f2bf(pv[nt] * inv);
            }
        }
        __syncthreads();

        f32x4 oacc[2];
        #pragma unroll
        for (int nt = 0; nt < 2; nt++) oacc[nt] = (f32x4){0.f,0.f,0.f,0.f};
        #pragma unroll
        for (int kst = 0; kst < 2; kst++){
            bf16x8 a = *(const bf16x8*)&ps[wv*16 + lrow][kst*32 + lkg*8];
            #pragma unroll
            for (int nt = 0; nt < 2; nt++){
                bf16x8 bb = *(const bf16x8*)&vt[nt*16 + lrow][kst*32 + lkg*8];
                oacc[nt] = __builtin_amdgcn_mfma_f32_16x16x32_bf16(a, bb, oacc[nt], 0, 0, 0);
            }
        }
        #pragma unroll
        for (int nt = 0; nt < 2; nt++)
            #pragma unroll
            for (int r = 0; r < 4; r++)
                qs[wv*16 + lkg*4 + r][nt*16 + lrow] = f2bf(oacc[nt][r]);
        __syncthreads();

        #pragma unroll
        for (int mt3 = 0; mt3 < 3; mt3++){
            int o = wv*48 + mt3*16 + lrow;
            bf16x8 a = *(const bf16x8*)&wpb[(size_t)o*C3 + h*32 + lkg*8];
            #pragma unroll
            for (int nt = 0; nt < 4; nt++){
                bf16x8 bb = *(const bf16x8*)&qs[nt*16 + lrow][lkg*8];
                pacc[mt3][nt] = __builtin_amdgcn_mfma_f32_16x16x32_bf16(a, bb, pacc[mt3][nt], 0, 0, 0);
            }
        }
        __syncthreads();
    }

    #pragma unroll
    for (int mt3 = 0; mt3 < 3; mt3++){
        #pragma unroll
        for (int r = 0; r < 4; r++){
            int o = wv*48 + mt3*16 + lkg*4 + r;
            float bias = bproj[o];
            float gf = 1.0f + gc * (gate[b*C3 + o] - 0.5f) * 2.0f;
            #pragma unroll
            for (int nt = 0; nt < 4; nt++){
                int token = nt*16 + lrow;
                size_t gi = wbase + (size_t)o*64 + token;
                float orig = bf2f(high[gi]);
                high[gi] = f2bf((orig + gm*(pacc[mt3][nt][r] + bias)) * gf);
            }
        }
    }
}

// ---------------- aux depthwise 3x3 + gelu
__global__ __launch_bounds__(256) void k_dwc_aux(const float* __restrict__ ll, const float* __restrict__ dw,
                                                 float* __restrict__ tmp, int nb){
    int idx = blockIdx.x*256 + threadIdx.x;
    int total = nb << 17;
    if (idx >= total) return;
    int c0 = (idx & 31) * 4;
    int h  = (idx >> 5) & 127;
    int ch = (idx >> 12) & 63;
    int b  = idx >> 18;
    const float* wd = dw + ch*9;
    const float* plane = ll + (((size_t)b*64 + ch) << 14);
    float acc[4] = {0.f, 0.f, 0.f, 0.f};
    #pragma unroll
    for (int dy = 0; dy < 3; dy++){
        int y = h + dy - 1;
        if (y < 0 || y > 127) continue;
        const float* rp = plane + y*128;
        float4 v = *(const float4*)(rp + c0);
        float l = (c0 > 0)   ? rp[c0 - 1] : 0.f;
        float rg = (c0 < 124) ? rp[c0 + 4] : 0.f;
        float w0 = wd[dy*3+0], w1 = wd[dy*3+1], w2 = wd[dy*3+2];
        acc[0] += w0*l   + w1*v.x + w2*v.y;
        acc[1] += w0*v.x + w1*v.y + w2*v.z;
        acc[2] += w0*v.y + w1*v.z + w2*v.w;
        acc[3] += w0*v.z + w1*v.w + w2*rg;
    }
    float4 o;
    o.x = gelu_f(acc[0]); o.y = gelu_f(acc[1]); o.z = gelu_f(acc[2]); o.w = gelu_f(acc[3]);
    *(float4*)&tmp[(((size_t)b*64 + ch) << 14) + h*128 + c0] = o;
}

// ---------------- aux pointwise, LDS-tiled
__global__ __launch_bounds__(256) void k_aux_pw(const float* __restrict__ ll, const float* __restrict__ tmp,
                                                const float* __restrict__ pw, const float* __restrict__ ga_p,
                                                float* __restrict__ rll, int nb){
    __shared__ float tl[64][65];
    int tid = threadIdx.x;
    int blk = blockIdx.x;
    int b = blk >> 8;
    int pix0 = (blk & 255) * 64;
    for (int idx = tid; idx < 4096; idx += 256){
        int c = idx >> 6, px = idx & 63;
        tl[c][px] = tmp[((size_t)(b*64 + c) << 14) + pix0 + px];
    }
    __syncthreads();
    int px = tid & 63, cq = tid >> 6;
    float ga = ga_p[0];
    for (int og = 0; og < 2; og++){
        int ob = cq*16 + og*8;
        float acc[8] = {0,0,0,0,0,0,0,0};
        for (int c = 0; c < 64; c++){
            float v = tl[c][px];
            #pragma unroll
            for (int j = 0; j < 8; j++) acc[j] += v * pw[(ob+j)*64 + c];
        }
        #pragma unroll
        for (int j = 0; j < 8; j++){
            size_t gi = ((size_t)(b*64 + ob + j) << 14) + pix0 + px;
            rll[gi] = ll[gi] + ga * acc[j];
        }
    }
}

// ---------------- IWT + (iwt - x) @ attn_out_w.T + x -> y1 (bf16)
__global__ __launch_bounds__(256) void k_iwt_proj(const float* __restrict__ rll,
    const unsigned short* __restrict__ high,
    const float* __restrict__ x, const float* __restrict__ wao,
    unsigned short* __restrict__ y1b, int nb, int b0){
    __shared__ float wt[64][65];
    __shared__ float dbuf[64][65];
    __shared__ float xt[64][65];
    int tid = threadIdx.x;
    for (int idx = tid; idx < 4096; idx += 256){
        int o = idx >> 6, i = idx & 63;
        wt[i][o] = wao[o*64 + i];
    }
    int blk = blockIdx.x;
    int seg = blk & 3;
    int ph  = (blk >> 2) & 255;
    int b   = blk >> 10;
    int pw0 = seg * 64;
    int h2 = ph >> 1, p = ph & 1;
    size_t xbase = ((size_t)(b0 + b) * DIMC) * 65536;
    int px = tid & 63;
    int ci = tid >> 6;
    int pwv = pw0 + px;
    int w2 = pwv >> 1, q = pwv & 1;
    float shl = q ? 1.f : -1.f;
    float slh = p ? 1.f : -1.f;
    float shh = (p == q) ? 1.f : -1.f;
    int hs = (h2 + SHIFTV) & 127; int wh = hs >> 3; int rr = hs & 7;
    int ws = (w2 + SHIFTV) & 127; int ww = ws >> 3; int cc = ws & 7;
    size_t wbase = ((size_t)(b*256 + wh*16 + ww)) * 12288 + rr*8 + cc;
    for (int i = ci; i < 64; i += 4){
        float llv = rll[(((size_t)b*64 + i)*128 + h2)*128 + w2];
        float hl = bf2f(high[wbase + (size_t)i*64]);
        float lh = bf2f(high[wbase + (size_t)(64 + i)*64]);
        float hh = bf2f(high[wbase + (size_t)(128 + i)*64]);
        float iw = 0.5f * (llv + shl*hl + slh*lh + shh*hh);
        float xv = x[xbase + (size_t)i*65536 + (size_t)ph*256 + pwv];
        xt[i][px] = xv;
        dbuf[i][px] = iw - xv;
    }
    __syncthreads();
    for (int o = ci; o < 64; o += 4){
        float s0=0.f,s1=0.f,s2=0.f,s3=0.f;
        for (int i = 0; i < 64; i += 4){
            s0 += dbuf[i+0][px] * wt[i+0][o];
            s1 += dbuf[i+1][px] * wt[i+1][o];
            s2 += dbuf[i+2][px] * wt[i+2][o];
            s3 += dbuf[i+3][px] * wt[i+3][o];
        }
        y1b[(((size_t)(b*64 + o)) << 16) + (size_t)ph*256 + pwv] =
            f2bf(xt[o][px] + (s0+s1)+(s2+s3));
    }
}

// ---------------- spectral kernel: k_c = irfft2(W_c)
__global__ __launch_bounds__(256) void k_kspec(const float* __restrict__ wr, const float* __restrict__ wi,
                                               float* __restrict__ ks){
    int idx = blockIdx.x*256 + threadIdx.x;
    if (idx >= 128*64) return;
    int ch = idx >> 6;
    int r = (idx >> 3) & 7, c = idx & 7;
    float s = 0.f;
    for (int u = 0; u < 8; u++){
        for (int v = 0; v < 8; v++){
            float re, im;
            if (v <= 4){ re = wr[ch*40 + u*5 + v]; im = wi[ch*40 + u*5 + v]; }
            else { int u2 = (8-u)&7; int v2 = 8-v; re = wr[ch*40 + u2*5 + v2]; im = -wi[ch*40 + u2*5 + v2]; }
            float ang = (float)(u*r + v*c) * 0.78539816339744831f;
            float cs, sn; __sincosf(ang, &sn, &cs);
            s += re * cs - im * sn;
        }
    }
    ks[idx] = s * (1.0f/64.0f);
}

// ---------------- circulant matrices (bf16)
__global__ __launch_bounds__(256) void k_circ(const float* __restrict__ ksp, unsigned short* __restrict__ circ){
    int idx = blockIdx.x*256 + threadIdx.x;
    if (idx >= 128*4096) return;
    int ch = idx >> 12;
    int o = (idx >> 6) & 63;
    int i = idx & 63;
    int dr = ((o >> 3) - (i >> 3)) & 7;
    int dc = ((o & 7) - (i & 7)) & 7;
    circ[idx] = f2bf(ksp[ch*64 + dr*8 + dc]);
}

// ---------------- FFN part A: LN + conv1x1(64->256) via MFMA, bf16 in/out
__global__ __launch_bounds__(256) void k_ffn_a(const unsigned short* __restrict__ y1b,
    const float* __restrict__ lnw, const float* __restrict__ lnb,
    const unsigned short* __restrict__ wib, unsigned short* __restrict__ h, int nb)
{
    __shared__ float yl[64][72];
    __shared__ __align__(16) unsigned short xn[64][72];
    __shared__ __align__(16) unsigned short ho[128][72];
    __shared__ float mu_s[64], rs_s[64];
    int tid = threadIdx.x;
    int lane = tid & 63;
    int wv = tid >> 6;
    int lrow = lane & 15;
    int lkg  = lane >> 4;
    int blk = blockIdx.x;
    int b   = blk >> 10;
    int row = (blk >> 2) & 255;
    int q   = blk & 3;

    for (int idx = tid; idx < 512; idx += 256){
        int c = idx >> 3, p8 = idx & 7;
        bf16x8 v = *(const bf16x8*)&y1b[((size_t)(b*64 + c) << 16) + (size_t)row*256 + q*64 + p8*8];
        #pragma unroll
        for (int j = 0; j < 8; j++) yl[c][p8*8 + j] = bf2f((unsigned short)v[j]);
    }
    __syncthreads();
    if (tid < 64){
        float s = 0.f, ss = 0.f;
        for (int c = 0; c < 64; c++){ float v = yl[c][tid]; s += v; ss += v*v; }
        float mu = s * (1.f/64.f), var = ss * (1.f/64.f) - mu*mu;
        mu_s[tid] = mu; rs_s[tid] = rsqrtf(var + 1e-6f);
    }
    __syncthreads();
    for (int idx = tid; idx < 4096; idx += 256){
        int px = idx & 63, c = idx >> 6;
        xn[px][c] = f2bf((yl[c][px] - mu_s[px]) * rs_s[px] * lnw[c] + lnb[c]);
    }
    __syncthreads();

    for (int hh = 0; hh < 2; hh++){
        int oc0 = hh*128;
        f32x4 acc[8];
        #pragma unroll
        for (int nt = 0; nt < 8; nt++) acc[nt] = (f32x4){0.f,0.f,0.f,0.f};
        #pragma unroll
        for (int kst = 0; kst < 2; kst++){
            bf16x8 a = *(const bf16x8*)&xn[wv*16 + lrow][kst*32 + lkg*8];
            #pragma unroll
            for (int nt = 0; nt < 8; nt++){
                bf16x8 bb = *(const bf16x8*)&wib[(size_t)(oc0 + nt*16 + lrow)*64 + kst*32 + lkg*8];
                acc[nt] = __builtin_amdgcn_mfma_f32_16x16x32_bf16(a, bb, acc[nt], 0, 0, 0);
            }
        }
        #pragma unroll
        for (int nt = 0; nt < 8; nt++)
            #pragma unroll
            for (int r = 0; r < 4; r++)
                ho[nt*16 + lrow][wv*16 + lkg*4 + r] = f2bf(acc[nt][r]);
        __syncthreads();
        for (int idx = tid; idx < 1024; idx += 256){
            int oc = idx >> 3, p8 = idx & 7;
            bf16x8 v = *(const bf16x8*)&ho[oc][p8*8];
            *(bf16x8*)&h[(size_t)(b*256 + oc0 + oc)*65536 + (size_t)row*256 + q*64 + p8*8] = v;
        }
        __syncthreads();
    }
}

// ---------------- FFN part B: depthwise 3x3 (8 px/thread, vectorized) -> patch-major hd
__global__ __launch_bounds__(256) void k_ffn_b(const unsigned short* __restrict__ h,
    const float* __restrict__ w_dw, unsigned short* __restrict__ hd, int nb)
{
    int chunk = blockIdx.x*256 + threadIdx.x;
    int total = nb*256*8192;
    if (chunk >= total) return;
    int c0  = (chunk & 31) * 8;
    int r   = (chunk >> 5) & 255;
    int bch = chunk >> 13;
    int ch  = bch & 255;
    const unsigned short* hp = h + ((size_t)bch << 16);
    const float* wd = w_dw + ch*9;
    float acc[8] = {0,0,0,0,0,0,0,0};
    #pragma unroll
    for (int dy = 0; dy < 3; dy++){
        int y = r + dy - 1;
        if (y < 0 || y > 255) continue;
        const unsigned short* rp = hp + y*256;
        bf16x8 v = *(const bf16x8*)&rp[c0];
        float vf[8];
        #pragma unroll
        for (int j = 0; j < 8; j++) vf[j] = bf2f((unsigned short)v[j]);
        float l  = (c0 > 0)   ? bf2f(rp[c0 - 1]) : 0.f;
        float rg = (c0 < 248) ? bf2f(rp[c0 + 8]) : 0.f;
        float w0 = wd[dy*3+0], w1 = wd[dy*3+1], w2 = wd[dy*3+2];
        acc[0] += w0*l + w1*vf[0] + w2*vf[1];
        #pragma unroll
        for (int j = 1; j < 7; j++) acc[j] += w0*vf[j-1] + w1*vf[j] + w2*vf[j+1];
        acc[7] += w0*vf[6] + w1*vf[7] + w2*rg;
    }
    bf16x8 o;
    #pragma unroll
    for (int j = 0; j < 8; j++) o[j] = (short)f2bf(acc[j]);
    int patch = (r >> 3)*32 + (c0 >> 3);
    *(bf16x8*)&hd[((size_t)bch << 16) + (size_t)patch*64 + (r & 7)*8] = o;
}

// ---------------- FFN spectral conv via MFMA circulant GEMM + gelu*gate -> m (bf16)
__global__ __launch_bounds__(256) void k_conv(const unsigned short* __restrict__ hdu,
    const unsigned short* __restrict__ circ, unsigned short* __restrict__ mbuf)
{
    int tid = threadIdx.x;
    int lane = tid & 63;
    int wv = tid >> 6;
    int lrow = lane & 15;
    int lkg  = lane >> 4;
    int blk = blockIdx.x;
    int b   = blk >> 7;
    int chc = (blk >> 5) & 3;
    int pc  = blk & 31;
    int pbase  = pc*32 + (wv >> 1)*16;
    int chbase = chc*32 + (wv & 1)*16;

    for (int c16 = 0; c16 < 16; c16++){
        int ch = chbase + c16;
        const unsigned short* Ab = hdu + (((size_t)(b*256 + ch)) << 16);
        const unsigned short* Bb = circ + (size_t)ch*4096;
        f32x4 acc[4];
        #pragma unroll
        for (int nt = 0; nt < 4; nt++) acc[nt] = (f32x4){0.f,0.f,0.f,0.f};
        #pragma unroll
        for (int kst = 0; kst < 2; kst++){
            bf16x8 a = *(const bf16x8*)&Ab[(size_t)(pbase + lrow)*64 + kst*32 + lkg*8];
            #pragma unroll
            for (int nt = 0; nt < 4; nt++){
                bf16x8 bb = *(const bf16x8*)&Bb[(size_t)(nt*16 + lrow)*64 + kst*32 + lkg*8];
                acc[nt] = __builtin_amdgcn_mfma_f32_16x16x32_bf16(a, bb, acc[nt], 0, 0, 0);
            }
        }
        const unsigned short* Gb = hdu + (((size_t)(b*256 + 128 + ch)) << 16);
        unsigned short* Mb = mbuf + (((size_t)(b*128 + ch)) << 16);
        #pragma unroll
        for (int nt = 0; nt < 4; nt++){
            #pragma unroll
            for (int r = 0; r < 4; r++){
                int patch = pbase + lkg*4 + r;
                int px = nt*16 + lrow;
                float g = bf2f(Gb[(size_t)patch*64 + px]);
                Mb[(size_t)patch*64 + px] = f2bf(gelu_f(acc[nt][r]) * g);
            }
        }
    }
}

// ---------------- FFN out-projection via MFMA: out = y1 + m @ w_out.T
__global__ __launch_bounds__(256) void k_out(const unsigned short* __restrict__ y1b,
    const unsigned short* __restrict__ mbuf, const unsigned short* __restrict__ wob,
    float* __restrict__ out, int b0)
{
    __shared__ __align__(16) unsigned short mlds[2][64][136];
    int tid = threadIdx.x;
    int lane = tid & 63;
    int wv = tid >> 6;
    int lrow = lane & 15;
    int lkg  = lane >> 4;
    int blk = blockIdx.x;
    int b  = blk >> 9;
    int pp = blk & 511;

    for (int it = 0; it < 8; it++){
        int chunk = tid + it*256;
        int ch = chunk >> 4;
        int p = (chunk >> 3) & 1;
        int px8 = chunk & 7;
        bf16x8 v = *(const bf16x8*)&mbuf[(((size_t)(b*128 + ch)) << 16) + (size_t)(2*pp + p)*64 + px8*8];
        #pragma unroll
        for (int j = 0; j < 8; j++) mlds[p][px8*8 + j][ch] = (unsigned short)v[j];
    }
    __syncthreads();

    int p = wv >> 1;
    int ochalf = wv & 1;
    f32x4 acc[2][4];
    #pragma unroll
    for (int mt = 0; mt < 2; mt++)
        #pragma unroll
        for (int nt = 0; nt < 4; nt++) acc[mt][nt] = (f32x4){0.f,0.f,0.f,0.f};
    #pragma unroll
    for (int kst = 0; kst < 4; kst++){
        bf16x8 a0 = *(const bf16x8*)&wob[(size_t)(ochalf*32 + 0  + lrow)*128 + kst*32 + lkg*8];
        bf16x8 a1 = *(const bf16x8*)&wob[(size_t)(ochalf*32 + 16 + lrow)*128 + kst*32 + lkg*8];
        #pragma unroll
        for (int nt = 0; nt < 4; nt++){
            bf16x8 bb = *(const bf16x8*)&mlds[p][nt*16 + lrow][kst*32 + lkg*8];
            acc[0][nt] = __builtin_amdgcn_mfma_f32_16x16x32_bf16(a0, bb, acc[0][nt], 0, 0, 0);
            acc[1][nt] = __builtin_amdgcn_mfma_f32_16x16x32_bf16(a1, bb, acc[1][nt], 0, 0, 0);
        }
    }
    int patchIdx = 2*pp + p;
    int Rb = (patchIdx >> 5) * 8, Cb = (patchIdx & 31) * 8;
    #pragma unroll
    for (int mt = 0; mt < 2; mt++){
        #pragma unroll
        for (int nt = 0; nt < 4; nt++){
            #pragma unroll
            for (int r = 0; r < 4; r++){
                int oc = ochalf*32 + mt*16 + lkg*4 + r;
                int px = nt*16 + lrow;
                int R = Rb + (px >> 3), C = Cb + (px & 7);
                size_t li = (((size_t)(b*64 + oc)) << 16) + (size_t)R*256 + C;
                size_t go = (((size_t)((b0 + b)*64 + oc)) << 16) + (size_t)R*256 + C;
                out[go] = bf2f(y1b[li]) + acc[mt][nt][r];
            }
        }
    }
}

extern "C" void kernel_launch(void* const* d_in, const int* in_sizes, int n_in,
                              void* d_out, int out_size, void* d_ws, size_t ws_size,
                              hipStream_t stream){
    const float* x        = (const float*)d_in[0];
    const float* ln_w     = (const float*)d_in[1];
    const float* ln_b     = (const float*)d_in[2];
    const float* lnh_w    = (const float*)d_in[3];
    const float* lnh_b    = (const float*)d_in[4];
    const float* w_qkv    = (const float*)d_in[5];
    const float* b_qkv    = (const float*)d_in[6];
    const float* w_proj   = (const float*)d_in[7];
    const float* b_proj   = (const float*)d_in[8];
    const float* rel_tab  = (const float*)d_in[9];
    const float* g_main   = (const float*)d_in[10];
    const float* g_aux    = (const float*)d_in[11];
    const float* g_cross  = (const float*)d_in[12];
    const float* aux_dw   = (const float*)d_in[13];
    const float* aux_pw   = (const float*)d_in[14];
    const float* cg_w1    = (const float*)d_in[15];
    const float* cg_w2    = (const float*)d_in[16];
    const float* attn_ow  = (const float*)d_in[17];
    const float* ffn_in_w = (const float*)d_in[18];
    const float* ffn_dw   = (const float*)d_in[19];
    const float* ffn_ow   = (const float*)d_in[20];
    const float* wb_re    = (const float*)d_in[21];
    const float* wb_im    = (const float*)d_in[22];
    const int*   rel_idx  = (const int*)d_in[23];
    float* out = (float*)d_out;
    (void)in_sizes; (void)n_in; (void)out_size;

    const size_t MBsz = (size_t)1 << 20;
    auto need = [&](int nb)->size_t { return (size_t)nb*72*MBsz + 2*MBsz; };
    int nbmax = 4;
    while (nbmax > 1 && need(nbmax) > ws_size) nbmax >>= 1;

    for (int b0 = 0; b0 < 4; b0 += nbmax){
        int nb = nbmax;
        char* p = (char*)d_ws;
        char* U = p;                      p += (size_t)nb*72*MBsz;
        float* gap  = (float*)p;          p += 4096;
        float* gate = (float*)p;          p += 4096;
        float* ksp  = (float*)p;          p += 128*64*4;
        unsigned short* wqb = (unsigned short*)p; p += 576*192*2;
        unsigned short* wpb = (unsigned short*)p; p += 192*192*2;
        float* bias6 = (float*)p;         p += 6*64*64*4;
        unsigned short* circ = (unsigned short*)p; p += 128*4096*2;
        unsigned short* wob  = (unsigned short*)p; p += 64*128*2;
        unsigned short* wib  = (unsigned short*)p; p += 256*64*2;

        // phase-1 overlays (all inside hd's future region [0, nb*32MB))
        float* ll            = (float*)U;                                   // nb*4MB
        unsigned short* highb= (unsigned short*)(U + (size_t)nb*4*MBsz);    // nb*6MB
        float* tmp           = (float*)(U + (size_t)nb*10*MBsz);            // nb*4MB
        float* rll           = (float*)(U + (size_t)nb*14*MBsz);            // nb*4MB
        // phase-2
        unsigned short* hd   = (unsigned short*)U;                          // nb*32MB [0..32)
        unsigned short* h    = (unsigned short*)(U + (size_t)nb*32*MBsz);   // nb*32MB [32..64)
        unsigned short* y1b  = (unsigned short*)(U + (size_t)nb*64*MBsz);   // nb*8MB  [64..72)
        unsigned short* mbuf = (unsigned short*)(U + (size_t)nb*32*MBsz);   // nb*16MB overlays dead h

        k_kspec<<<32, 256, 0, stream>>>(wb_re, wb_im, ksp);
        k_circ<<<2048, 256, 0, stream>>>(ksp, circ);
        k_cvt<<<432, 256, 0, stream>>>(w_qkv, w_proj, rel_tab, rel_idx, ffn_ow, ffn_in_w,
                                       wqb, wpb, bias6, wob, wib);
        k_dwt<<<nb*2048, 256, 0, stream>>>(x, ll, highb, nb, b0);
        k_gap<<<nb*64, 256, 0, stream>>>(ll, gap);
        k_gate<<<nb, 256, 0, stream>>>(gap, cg_w1, cg_w2, gate);
        k_attn<<<nb*256, 256, 0, stream>>>(highb, wqb, wpb, b_qkv, b_proj, bias6,
                                           lnh_w, lnh_b, gate, g_main, g_cross);
        k_dwc_aux<<<nb*512, 256, 0, stream>>>(ll, aux_dw, tmp, nb);
        k_aux_pw<<<nb*256, 256, 0, stream>>>(ll, tmp, aux_pw, g_aux, rll, nb);
        k_iwt_proj<<<nb*1024, 256, 0, stream>>>(rll, highb, x, attn_ow, y1b, nb, b0);
        k_ffn_a<<<nb*1024, 256, 0, stream>>>(y1b, ln_w, ln_b, wib, h, nb);
        k_ffn_b<<<nb*8192, 256, 0, stream>>>(h, ffn_dw, hd, nb);
        k_conv<<<nb*128, 256, 0, stream>>>(hd, circ, mbuf);
        k_out<<<nb*512, 256, 0, stream>>>(y1b, mbuf, wob, out, b0);
    }
}